// Round 9
// baseline (266.766 us; speedup 1.0000x reference)
//
#include <hip/hip_runtime.h>
#include <hip/hip_bf16.h>
#include <math.h>

#define T_ 2048
#define H_ 16
#define KH_ 2
#define G_ 8
#define D_ 128
#define NCMP 127
#define JP 128
#define NBLK 32
#define TOPN 16
#define WIN_ 512
#define SCALE 0.08838834764831845f
#define SCL2 (0.08838834764831845f * 1.4426950408889634f)   // SCALE * log2(e)
#define THR2 11.541560f                                      // 8 * log2(e)

typedef __attribute__((ext_vector_type(8))) short short8;
typedef __attribute__((ext_vector_type(16))) float f32x16;

__device__ __forceinline__ unsigned short f2bf(float x) {
    union { float f; unsigned u; } c; c.f = x;
    unsigned u = c.u + 0x7fffu + ((c.u >> 16) & 1u);
    return (unsigned short)(u >> 16);
}
__device__ __forceinline__ float bf2f(unsigned short b) {
    union { unsigned u; float f; } c; c.u = (unsigned)b << 16; return c.f;
}
__device__ __forceinline__ float exp2_fast(float x) {
    float r;
    asm("v_exp_f32 %0, %1" : "=v"(r) : "v"(x));
    return r;
}

// ---------- kernel 0: K/V -> bf16 FRAGMENT-MAJOR images ----------------------
// Per tile (kh,b), 8192 halves each:
//   kimgF [c8*512  + r*8 + e] = K[s0+r][c8*8+e]        (r<64,  c8<16)
//   vtimgF[kc8*1024 + d*8 + e] = V[s0+kc8*8+e][d]      (d<128, kc8<8)
// -> a wave's 16B/lane fragment read = two contiguous 512B segments (coalesced).
__global__ __launch_bounds__(256) void prep_kv(
        const float* __restrict__ k, const float* __restrict__ v,
        unsigned short* __restrict__ kimg, unsigned short* __restrict__ vtimg) {
    const int b  = blockIdx.x;
    const int kh = blockIdx.y;
    const int s0 = b << 6;
    const int tid = threadIdx.x;
    const size_t tb = ((size_t)kh * 32 + b) * 8192;
#pragma unroll
    for (int it = 0; it < 4; ++it) {
        int idx = it * 256 + tid;
        int r = idx >> 4, c = idx & 15;
        const float* src = k + (size_t)(s0 + r) * (KH_ * D_) + kh * D_ + c * 8;
        float4 x = *reinterpret_cast<const float4*>(src);
        float4 y = *reinterpret_cast<const float4*>(src + 4);
        union { unsigned short u[8]; uint4 q; } o;
        o.u[0] = f2bf(x.x); o.u[1] = f2bf(x.y); o.u[2] = f2bf(x.z); o.u[3] = f2bf(x.w);
        o.u[4] = f2bf(y.x); o.u[5] = f2bf(y.y); o.u[6] = f2bf(y.z); o.u[7] = f2bf(y.w);
        *reinterpret_cast<uint4*>(&kimg[tb + c * 512 + r * 8]) = o.q;
    }
#pragma unroll
    for (int it = 0; it < 4; ++it) {
        int idx = it * 256 + tid;
        int d = idx & 127, kc8 = idx >> 7;
        union { unsigned short u[8]; uint4 q; } o;
#pragma unroll
        for (int e = 0; e < 8; ++e)
            o.u[e] = f2bf(v[(size_t)(s0 + kc8 * 8 + e) * (KH_ * D_) + kh * D_ + d]);
        *reinterpret_cast<uint4*>(&vtimg[tb + kc8 * 1024 + d * 8]) = o.q;
    }
}

// ---------- kernel 1: compressed means -> khiF/kloF/cvtF (fragment-major) -----
//   khiF/kloF[(c8*128 + j)*8 + e] = cmp_k hi/lo, c8 = d>>3, e = d&7  (j<128)
//   cvtF    [(jc8*128 + d)*8 + e] = cmp_v[jc8*8+e][d]
__global__ __launch_bounds__(128) void build_cmp(
        const float* __restrict__ k, const float* __restrict__ v,
        unsigned short* __restrict__ khiF, unsigned short* __restrict__ kloF,
        unsigned short* __restrict__ cvtF) {
    int j  = blockIdx.x;
    int kh = blockIdx.y;
    int d  = threadIdx.x;
    unsigned short hb = 0, lb = 0, vb = 0;
    if (j < NCMP) {
        int s0 = j * 16;
        float sk = 0.f, sv = 0.f;
        for (int i = 0; i < 32; ++i) {
            sk += k[(size_t)(s0 + i) * KH_ * D_ + kh * D_ + d];
            sv += v[(size_t)(s0 + i) * KH_ * D_ + kh * D_ + d];
        }
        float mk = sk * (1.f / 32.f), mv = sv * (1.f / 32.f);
        hb = f2bf(mk);
        lb = f2bf(mk - bf2f(hb));
        vb = f2bf(mv);
    }
    size_t base = (size_t)kh * 16384;
    size_t ib = base + (d >> 3) * 1024 + j * 8 + (d & 7);
    khiF[ib] = hb;
    kloF[ib] = lb;
    cvtF[base + (j >> 3) * 1024 + d * 8 + (j & 7)] = vb;
}

// ---------- kernel 2: MFMA compressed attention + top-16 (direct-global) ------
// Operands read straight from the fragment-major images in L2 (no staging, no
// staging barrier). LDS only for the cross-wave window/block-score reduction.
__global__ __launch_bounds__(256, 1) void cmp_attn_mfma(
        const float* __restrict__ q, const float* __restrict__ w,
        const unsigned short* __restrict__ khiF, const unsigned short* __restrict__ kloF,
        const unsigned short* __restrict__ cvtF,
        float* __restrict__ out, unsigned int* __restrict__ sel) {
    const int qt  = blockIdx.x;
    const int kh  = blockIdx.y;
    const int t0  = qt * 16;
    const int tid = threadIdx.x;
    const int wv  = tid >> 6;
    const int lane = tid & 63;
    const int l31 = lane & 31;
    const int hi  = lane >> 5;
    const int hi4 = hi * 4;

    __shared__ float wsc_s[16 * 132];
    __shared__ float bsc_s[16 * 32];
    __shared__ unsigned int sel_s[16];

    if (tid < 16) sel_s[tid] = 0u;
    for (int i = tid; i < 16 * 132; i += 256) wsc_s[i] = 0.f;
    __syncthreads();    // zeros visible before any wave's atomics

    const unsigned short* KH = khiF + (size_t)kh * 16384;
    const unsigned short* KL = kloF + (size_t)kh * 16384;
    const unsigned short* CV = cvtF + (size_t)kh * 16384;

    const int qloc = l31 & 15;
    const int t    = t0 + qloc;
    const int h    = kh * G_ + 2 * wv + (l31 >> 4);
    short8 qhi[8], qlo[8];
    {
        const float* qrow = q + (size_t)t * (H_ * D_) + h * D_;
#pragma unroll
        for (int dc = 0; dc < 8; ++dc) {
            int d0 = dc * 16 + hi * 8;
            float4 x = *reinterpret_cast<const float4*>(qrow + d0);
            float4 y = *reinterpret_cast<const float4*>(qrow + d0 + 4);
            float e_[8] = {x.x, x.y, x.z, x.w, y.x, y.y, y.z, y.w};
            short8 fh, fl;
#pragma unroll
            for (int e = 0; e < 8; ++e) {
                unsigned short hb = f2bf(e_[e]);
                fh[e] = (short)hb;
                fl[e] = (short)f2bf(e_[e] - bf2f(hb));
            }
            qhi[dc] = fh; qlo[dc] = fl;
        }
    }

    // QK^T split-bf16: S^T[j][combo]; A-frags direct from L2
    f32x16 s_[4];
#pragma unroll
    for (int tl = 0; tl < 4; ++tl)
#pragma unroll
        for (int r = 0; r < 16; ++r) s_[tl][r] = 0.f;
#pragma unroll
    for (int dc = 0; dc < 8; ++dc) {
        int base = (dc * 2 + hi) * 1024 + l31 * 8;
#pragma unroll
        for (int tl = 0; tl < 4; ++tl) {
            int off = base + tl * 256;
            short8 ahi = *reinterpret_cast<const short8*>(&KH[off]);
            short8 alo = *reinterpret_cast<const short8*>(&KL[off]);
            s_[tl] = __builtin_amdgcn_mfma_f32_32x32x16_bf16(ahi, qhi[dc], s_[tl], 0, 0, 0);
            s_[tl] = __builtin_amdgcn_mfma_f32_32x32x16_bf16(alo, qhi[dc], s_[tl], 0, 0, 0);
            s_[tl] = __builtin_amdgcn_mfma_f32_32x32x16_bf16(ahi, qlo[dc], s_[tl], 0, 0, 0);
        }
    }

    const int nv = (t >= 31) ? (((t - 31) >> 4) + 1) : 0;
    float m = -1e30f;
#pragma unroll
    for (int tl = 0; tl < 4; ++tl)
#pragma unroll
        for (int r = 0; r < 16; ++r) {
            int j = tl * 32 + (r & 3) + 8 * (r >> 2) + hi4;
            float lg = (j < nv) ? s_[tl][r] * SCALE : -1e30f;
            s_[tl][r] = lg;
            m = fmaxf(m, lg);
        }
    m = fmaxf(m, __shfl_xor(m, 32));
    float lsum = 0.f;
#pragma unroll
    for (int tl = 0; tl < 4; ++tl)
#pragma unroll
        for (int r = 0; r < 16; ++r) {
            float e = __expf(s_[tl][r] - m);
            s_[tl][r] = e;
            lsum += e;
        }
    lsum += __shfl_xor(lsum, 32);
    const float linv = (nv > 0) ? 1.f / lsum : 0.f;

#pragma unroll
    for (int tl = 0; tl < 4; ++tl)
#pragma unroll
        for (int r = 0; r < 16; ++r) {
            int j = tl * 32 + (r & 3) + 8 * (r >> 2) + hi4;
            atomicAdd(&wsc_s[qloc * 132 + j], s_[tl][r] * linv);
        }

    // PV: B-frags direct from L2
    f32x16 acc[4];
#pragma unroll
    for (int dt = 0; dt < 4; ++dt)
#pragma unroll
        for (int r = 0; r < 16; ++r) acc[dt][r] = 0.f;
#pragma unroll
    for (int kc = 0; kc < 8; ++kc) {
        const int su = kc >> 1, rb = (kc & 1) * 8;
        unsigned pa0, pa1, pb0, pb1;
        asm("v_cvt_pk_bf16_f32 %0, %1, %2" : "=v"(pa0) : "v"(s_[su][rb+0]), "v"(s_[su][rb+1]));
        asm("v_cvt_pk_bf16_f32 %0, %1, %2" : "=v"(pa1) : "v"(s_[su][rb+2]), "v"(s_[su][rb+3]));
        asm("v_cvt_pk_bf16_f32 %0, %1, %2" : "=v"(pb0) : "v"(s_[su][rb+4]), "v"(s_[su][rb+5]));
        asm("v_cvt_pk_bf16_f32 %0, %1, %2" : "=v"(pb1) : "v"(s_[su][rb+6]), "v"(s_[su][rb+7]));
        unsigned sa0 = __shfl_xor(pa0, 32);
        unsigned sa1 = __shfl_xor(pa1, 32);
        unsigned sb0 = __shfl_xor(pb0, 32);
        unsigned sb1 = __shfl_xor(pb1, 32);
        union { unsigned u[4]; short8 s8; } pa;
        pa.u[0] = hi ? sb0 : pa0;
        pa.u[1] = hi ? sb1 : pa1;
        pa.u[2] = hi ? pb0 : sa0;
        pa.u[3] = hi ? pb1 : sa1;
        const int jc8 = kc * 2 + hi;
#pragma unroll
        for (int dt = 0; dt < 4; ++dt) {
            int d = dt * 32 + l31;
            short8 bf = *reinterpret_cast<const short8*>(&CV[jc8 * 1024 + d * 8]);
            acc[dt] = __builtin_amdgcn_mfma_f32_32x32x16_bf16(pa.s8, bf, acc[dt], 0, 0, 0);
        }
    }

    // epilogue: per-row w0/l via shfl (no LDS round-trip)
    float wfacv = w[(size_t)t * (H_ * 3) + h * 3 + 0] * linv;
    float wfr[16];
#pragma unroll
    for (int r = 0; r < 16; ++r)
        wfr[r] = __shfl(wfacv, (r & 3) + 8 * (r >> 2) + hi4);
#pragma unroll
    for (int dt = 0; dt < 4; ++dt)
#pragma unroll
        for (int r = 0; r < 16; ++r) {
            int crow = (r & 3) + 8 * (r >> 2) + hi4;
            int tt = t0 + (crow & 15);
            int hh = kh * G_ + 2 * wv + (crow >> 4);
            out[(size_t)tt * (H_ * D_) + hh * D_ + dt * 32 + l31] = acc[dt][r] * wfr[r];
        }

    __syncthreads();    // all waves' wsc atomics done

#pragma unroll
    for (int half = 0; half < 2; ++half) {
        int b  = (tid & 15) + half * 16;
        int qq = tid >> 4;
        int tt = t0 + qq;
        float sc = 0.f;
        int j0 = 4 * b - 1; if (j0 < 0) j0 = 0;
        int j1 = 4 * b + 3; if (j1 > NCMP - 1) j1 = NCMP - 1;
        for (int j = j0; j <= j1; ++j) sc += wsc_s[qq * 132 + j];
        int tb = tt >> 6;
        bool forced = (b == 0) || (b <= tb && b >= tb - 1);
        if (forced) sc = 1e30f;
        if (b * 64 > tt) sc = -1e30f;
        bsc_s[qq * 32 + b] = sc;
    }
    __syncthreads();

#pragma unroll
    for (int half = 0; half < 2; ++half) {
        int b  = (tid & 15) + half * 16;
        int qq = tid >> 4;
        float sb = bsc_s[qq * 32 + b];
        int cnt = 0;
        for (int b2 = 0; b2 < NBLK; ++b2) {
            float s2 = bsc_s[qq * 32 + b2];
            cnt += (s2 > sb) || (s2 == sb && b2 < b);
        }
        if (cnt < TOPN) atomicOr(&sel_s[qq], 1u << b);
    }
    __syncthreads();
    if (tid < 16) sel[kh * T_ + t0 + tid] = sel_s[tid];
}

// ---------- kernel 3: MFMA flash window+selected attention (direct-global) ----
// Zero LDS, zero barriers: each wave reads its MFMA fragments straight from the
// fragment-major images in L2. Block = 16 queries x 8 heads (4 waves), grid
// (128, KH, phase). Defer-max + exp2 + boundary-only masking as round 8.
__global__ __launch_bounds__(256, 2) void slc_win_mfma(
        const float* __restrict__ q, const unsigned short* __restrict__ kimg,
        const unsigned short* __restrict__ vtimg, const float* __restrict__ w,
        const unsigned int* __restrict__ sel, float* __restrict__ out,
        float* __restrict__ winb, float* __restrict__ slcb, int use_scratch) {
    const int phase = blockIdx.z;
    const int qt    = phase ? ((int)gridDim.x - 1 - (int)blockIdx.x) : (int)blockIdx.x;
    const int kh    = blockIdx.y;
    const int t0    = qt * 16;
    const int tid   = threadIdx.x;
    const int wv    = tid >> 6;
    const int lane  = tid & 63;
    const int l31   = lane & 31;
    const int hi    = lane >> 5;
    const int hi4   = hi * 4;

    const int qloc = l31 & 15;
    const int t    = t0 + qloc;
    const int h    = kh * G_ + 2 * wv + (l31 >> 4);

    // Q fragment, pre-scaled into exp2 domain
    short8 qf[8];
    {
        const float* qrow = q + (size_t)t * (H_ * D_) + h * D_;
#pragma unroll
        for (int dc = 0; dc < 8; ++dc) {
            int d0 = dc * 16 + hi * 8;
            float4 x = *reinterpret_cast<const float4*>(qrow + d0);
            float4 y = *reinterpret_cast<const float4*>(qrow + d0 + 4);
            short8 f;
            f[0] = (short)f2bf(x.x * SCL2); f[1] = (short)f2bf(x.y * SCL2);
            f[2] = (short)f2bf(x.z * SCL2); f[3] = (short)f2bf(x.w * SCL2);
            f[4] = (short)f2bf(y.x * SCL2); f[5] = (short)f2bf(y.y * SCL2);
            f[6] = (short)f2bf(y.z * SCL2); f[7] = (short)f2bf(y.w * SCL2);
            qf[dc] = f;
        }
    }

    const unsigned int smask = sel[kh * T_ + t];
    const int tbmax = t0 >> 6;
    unsigned int rem = 0;
    int bidx = 0;
    if (phase == 0) {
        int lo = t0 - (WIN_ - 1); if (lo < 0) lo = 0;
        bidx = lo >> 6;
    } else {
        unsigned int vm = (tbmax >= 31) ? 0xffffffffu : ((2u << tbmax) - 1u);
        rem = smask;
        rem |= __shfl_xor(rem, 1); rem |= __shfl_xor(rem, 2);
        rem |= __shfl_xor(rem, 4); rem |= __shfl_xor(rem, 8);
        rem &= vm;
    }

    f32x16 acc[4];
#pragma unroll
    for (int dt = 0; dt < 4; ++dt)
#pragma unroll
        for (int r = 0; r < 16; ++r) acc[dt][r] = 0.f;
    float m_run = -1e30f, l_run = 0.f;

    int b_cur;
    if (phase == 0) b_cur = bidx++;
    else { b_cur = rem ? (__ffs(rem) - 1) : -1; if (rem) rem &= rem - 1; }

    while (b_cur >= 0) {
        const int s0 = b_cur << 6;
        const unsigned short* Kt = kimg  + ((size_t)kh * 32 + b_cur) * 8192;
        const unsigned short* Vt = vtimg + ((size_t)kh * 32 + b_cur) * 8192;

        // ---- QK^T (swapped): A-frags direct from L2 ----
        f32x16 s_[2];
#pragma unroll
        for (int r = 0; r < 16; ++r) { s_[0][r] = 0.f; s_[1][r] = 0.f; }
#pragma unroll
        for (int dc = 0; dc < 8; ++dc) {
            int base = (dc * 2 + hi) * 512 + l31 * 8;
            short8 a0 = *reinterpret_cast<const short8*>(&Kt[base]);
            short8 a1 = *reinterpret_cast<const short8*>(&Kt[base + 256]);
            s_[0] = __builtin_amdgcn_mfma_f32_32x32x16_bf16(a0, qf[dc], s_[0], 0, 0, 0);
            s_[1] = __builtin_amdgcn_mfma_f32_32x32x16_bf16(a1, qf[dc], s_[1], 0, 0, 0);
        }

        // ---- masking: per-element only on boundary tiles ----
        const int sb = (smask >> b_cur) & 1;
        const bool needmask = (b_cur == tbmax) ||
                              ((phase == 0) && (s0 + 496 < t0));
        float mc = -1e30f;
        if (needmask) {
#pragma unroll
            for (int sub = 0; sub < 2; ++sub)
#pragma unroll
                for (int r = 0; r < 16; ++r) {
                    int crow = (r & 3) + 8 * (r >> 2) + hi4;
                    int s = s0 + sub * 32 + crow;
                    bool ok = (s <= t) && (phase ? (sb != 0) : (s + WIN_ > t));
                    float lg = ok ? s_[sub][r] : -1e30f;
                    s_[sub][r] = lg;
                    mc = fmaxf(mc, lg);
                }
        } else {
#pragma unroll
            for (int sub = 0; sub < 2; ++sub)
#pragma unroll
                for (int r = 0; r < 16; ++r) mc = fmaxf(mc, s_[sub][r]);
            if (phase) mc = sb ? mc : -1e30f;
        }

        // ---- defer-max rescale ----
        float f = 1.f;
        const bool resc = !__all(mc <= m_run + THR2);
        if (resc) {
            float wm = mc;
            wm = fmaxf(wm, __shfl_xor(wm, 1));
            wm = fmaxf(wm, __shfl_xor(wm, 2));
            wm = fmaxf(wm, __shfl_xor(wm, 4));
            wm = fmaxf(wm, __shfl_xor(wm, 8));
            wm = fmaxf(wm, __shfl_xor(wm, 16));
            wm = fmaxf(wm, __shfl_xor(wm, 32));
            float mnew = fmaxf(m_run, wm);
            f = exp2_fast(m_run - mnew);
            m_run = mnew;
        }

        float lsum = 0.f;
#pragma unroll
        for (int sub = 0; sub < 2; ++sub)
#pragma unroll
            for (int r = 0; r < 16; ++r) {
                float e = exp2_fast(s_[sub][r] - m_run);
                s_[sub][r] = e;
                lsum += e;
            }
        if (phase && !sb) lsum = 0.f;
        lsum += __shfl_xor(lsum, 32);
        if (resc) {
            l_run = l_run * f + lsum;
#pragma unroll
            for (int dt = 0; dt < 4; ++dt)
#pragma unroll
                for (int r = 0; r < 16; ++r) acc[dt][r] *= f;
        } else {
            l_run += lsum;
        }

        // ---- P -> bf16 A-frags; PV B-frags direct from L2 ----
        const unsigned zm = (phase && !sb) ? 0u : 0xffffffffu;
#pragma unroll
        for (int kc = 0; kc < 4; ++kc) {
            const int su = kc >> 1, rb = (kc & 1) * 8;
            unsigned pa0, pb0, pa1, pb1;
            asm("v_cvt_pk_bf16_f32 %0, %1, %2" : "=v"(pa0) : "v"(s_[su][rb+0]), "v"(s_[su][rb+1]));
            asm("v_cvt_pk_bf16_f32 %0, %1, %2" : "=v"(pa1) : "v"(s_[su][rb+2]), "v"(s_[su][rb+3]));
            asm("v_cvt_pk_bf16_f32 %0, %1, %2" : "=v"(pb0) : "v"(s_[su][rb+4]), "v"(s_[su][rb+5]));
            asm("v_cvt_pk_bf16_f32 %0, %1, %2" : "=v"(pb1) : "v"(s_[su][rb+6]), "v"(s_[su][rb+7]));
            unsigned sa0 = __shfl_xor(pa0, 32);
            unsigned sa1 = __shfl_xor(pa1, 32);
            unsigned sb0 = __shfl_xor(pb0, 32);
            unsigned sb1 = __shfl_xor(pb1, 32);
            union { unsigned u[4]; short8 s8; } pa;
            pa.u[0] = (hi ? sb0 : pa0) & zm;
            pa.u[1] = (hi ? sb1 : pa1) & zm;
            pa.u[2] = (hi ? pb0 : sa0) & zm;
            pa.u[3] = (hi ? pb1 : sa1) & zm;
            const int kc8 = kc * 2 + hi;
#pragma unroll
            for (int dt = 0; dt < 4; ++dt) {
                int d = dt * 32 + l31;
                short8 bf = *reinterpret_cast<const short8*>(&Vt[kc8 * 1024 + d * 8]);
                acc[dt] = __builtin_amdgcn_mfma_f32_32x32x16_bf16(pa.s8, bf, acc[dt], 0, 0, 0);
            }
        }

        if (phase == 0) b_cur = (bidx <= tbmax) ? bidx++ : -1;
        else { b_cur = rem ? (__ffs(rem) - 1) : -1; if (rem) rem &= rem - 1; }
    }

    // ---- epilogue: per-row w/l via shfl; plain stores to scratch ----
    float linv = 1.f / l_run;
    int widx = (phase == 0) ? 2 : 1;
    float wfacv = w[(size_t)t * (H_ * 3) + h * 3 + widx] * linv;
    float wfr[16];
#pragma unroll
    for (int r = 0; r < 16; ++r)
        wfr[r] = __shfl(wfacv, (r & 3) + 8 * (r >> 2) + hi4);
    float* base = (phase == 0) ? winb : slcb;
#pragma unroll
    for (int dt = 0; dt < 4; ++dt)
#pragma unroll
        for (int r = 0; r < 16; ++r) {
            int crow = (r & 3) + 8 * (r >> 2) + hi4;
            int tt = t0 + (crow & 15);
            int hh = kh * G_ + 2 * wv + (crow >> 4);
            size_t idx = (size_t)tt * (H_ * D_) + hh * D_ + dt * 32 + l31;
            float val = acc[dt][r] * wfr[r];
            if (use_scratch) base[idx] = val;
            else             atomicAdd(&out[idx], val);
        }
}

// ---------- kernel 4: combine (unchanged) -------------------------------------
__global__ __launch_bounds__(256) void combine_out(float* __restrict__ out,
        const float* __restrict__ a, const float* __restrict__ b) {
    int i = blockIdx.x * 256 + threadIdx.x;
    float4 o = reinterpret_cast<float4*>(out)[i];
    float4 x = reinterpret_cast<const float4*>(a)[i];
    float4 y = reinterpret_cast<const float4*>(b)[i];
    o.x += x.x + y.x; o.y += x.y + y.y; o.z += x.z + y.z; o.w += x.w + y.w;
    reinterpret_cast<float4*>(out)[i] = o;
}

// ---------- launch ----------
extern "C" void kernel_launch(void* const* d_in, const int* in_sizes, int n_in,
                              void* d_out, int out_size, void* d_ws, size_t ws_size,
                              hipStream_t stream) {
    const float* q = (const float*)d_in[0];
    const float* k = (const float*)d_in[1];
    const float* v = (const float*)d_in[2];
    const float* w = (const float*)d_in[3];
    float* out = (float*)d_out;

    char* ws = (char*)d_ws;
    unsigned short* kimg  = (unsigned short*)(ws);                    // 1 MB
    unsigned short* vtimg = (unsigned short*)(ws + (1u << 20));       // 1 MB
    unsigned short* khiF  = (unsigned short*)(ws + (2u << 20));       // 64 KB
    unsigned short* kloF  = (unsigned short*)(ws + (2u << 20) + 65536);
    unsigned short* cvtF  = (unsigned short*)(ws + (2u << 20) + 2 * 65536);
    unsigned int*   sel   = (unsigned int*)(ws + (2u << 20) + 3 * 65536);  // 16 KB
    float* winb_s = (float*)(ws + (2u << 20) + 3 * 65536 + 16384);
    float* slcb_s = winb_s + (size_t)T_ * H_ * D_;
    const size_t need = (2u << 20) + 3 * 65536 + 16384
                        + 2 * (size_t)T_ * H_ * D_ * sizeof(float);
    const int use_scratch = (ws_size >= need) ? 1 : 0;
    float* winb = use_scratch ? winb_s : out;
    float* slcb = use_scratch ? slcb_s : out;

    hipLaunchKernelGGL(prep_kv, dim3(32, KH_), dim3(256), 0, stream, k, v, kimg, vtimg);
    hipLaunchKernelGGL(build_cmp, dim3(128, KH_), dim3(128), 0, stream,
                       k, v, khiF, kloF, cvtF);
    hipLaunchKernelGGL(cmp_attn_mfma, dim3(T_ / 16, KH_), dim3(256), 0, stream,
                       q, w, khiF, kloF, cvtF, out, sel);
    hipLaunchKernelGGL(slc_win_mfma, dim3(T_ / 16, KH_, 2), dim3(256), 0, stream,
                       q, kimg, vtimg, w, sel, out, winb, slcb, use_scratch);
    if (use_scratch) {
        hipLaunchKernelGGL(combine_out, dim3((T_ * H_ * D_ / 4) / 256), dim3(256), 0, stream,
                           out, winb, slcb);
    }
}